// Round 5
// baseline (440.742 us; speedup 1.0000x reference)
//
#include <hip/hip_runtime.h>
#include <stdint.h>

typedef __bf16 bf16;
typedef __bf16 bf16x8 __attribute__((ext_vector_type(8)));
typedef __bf16 bf16x4 __attribute__((ext_vector_type(4)));
typedef float f32x4 __attribute__((ext_vector_type(4)));

constexpr int NB   = 32;
constexpr int CIN  = 1024;
constexpr int CB   = 256;
constexpr int COUT = 1024;
constexpr int HW   = 784;
constexpr int WIMG = 28;
constexpr int PW   = 30;    // padded width
constexpr int PHW  = 900;   // padded pixels per image

typedef const __attribute__((address_space(1))) void GV;
typedef __attribute__((address_space(3))) void LV;

// async global->LDS: dest = wave-uniform base, HW scatters lane*16; src per-lane gather.
__device__ __forceinline__ void gl16(const void* g, void* l) {
  __builtin_amdgcn_global_load_lds((GV*)(uintptr_t)g,
                                   (LV*)(uint32_t)(uintptr_t)l, 16, 0, 0);
}

// ---------------- zero padded o1p (border must be 0; ws re-poisoned every call)
__global__ __launch_bounds__(256) void k_zero(uint4* __restrict__ p, int n) {
  int i = blockIdx.x * 256 + threadIdx.x;
  if (i < n) { uint4 z; z.x = z.y = z.z = z.w = 0u; p[i] = z; }
}

// ---------------- x: fp32 NCHW -> bf16 NHWC
__global__ __launch_bounds__(256) void k_transpose(const float* __restrict__ x,
                                                   bf16* __restrict__ xT) {
  __shared__ bf16 tile[64][73];
  const int nb = blockIdx.z;
  const int p0 = blockIdx.x * 64;   // 13
  const int c0 = blockIdx.y * 64;   // 16
  const int tid = threadIdx.x;
#pragma unroll
  for (int it = 0; it < 4; ++it) {
    int idx = tid + it * 256;
    int row = idx >> 4, c4 = idx & 15;
    int p = p0 + c4 * 4;
    if (p < HW) {
      float4 v = *reinterpret_cast<const float4*>(x + (nb * CIN + c0 + row) * HW + p);
      tile[row][c4 * 4 + 0] = (bf16)v.x;
      tile[row][c4 * 4 + 1] = (bf16)v.y;
      tile[row][c4 * 4 + 2] = (bf16)v.z;
      tile[row][c4 * 4 + 3] = (bf16)v.w;
    }
  }
  __syncthreads();
#pragma unroll
  for (int it = 0; it < 2; ++it) {
    int idx = tid + it * 256;
    int pr = idx >> 3, c8 = idx & 7;
    if (p0 + pr < HW) {
      bf16x8 v;
#pragma unroll
      for (int j = 0; j < 8; ++j) v[j] = tile[c8 * 8 + j][pr];
      *reinterpret_cast<bf16x8*>(xT + (nb * HW + p0 + pr) * CIN + c0 + c8 * 8) = v;
    }
  }
}

// ---------------- w2: fp32 [co][ci][3][3] * s2[co] -> bf16 [co][rs][ci]
__global__ __launch_bounds__(256) void k_w2s(const float* __restrict__ w2,
                                             const float* __restrict__ s2,
                                             bf16* __restrict__ o) {
  int i = blockIdx.x * 256 + threadIdx.x;
  if (i < CB * 9 * CB) {
    int ci = i & 255;
    int t = i >> 8;
    int rs = t % 9;
    int co = t / 9;
    o[i] = (bf16)(w2[(co * CB + ci) * 9 + rs] * s2[co]);
  }
}

// ---------------- w (fp32 [co][K]) * s[co] -> bf16, K = 2^ksh
__global__ __launch_bounds__(256) void k_wscale(const float* __restrict__ w,
                                                const float* __restrict__ s,
                                                bf16* __restrict__ o, int n, int ksh) {
  int i = (blockIdx.x * 256 + threadIdx.x) * 4;
  if (i < n) {
    float sv = s[i >> ksh];
    float4 v = *reinterpret_cast<const float4*>(w + i);
    bf16x4 r;
    r[0] = (bf16)(v.x * sv); r[1] = (bf16)(v.y * sv);
    r[2] = (bf16)(v.z * sv); r[3] = (bf16)(v.w * sv);
    *reinterpret_cast<bf16x4*>(o + i) = r;
  }
}

// =====================================================================
// conv1/conv2: block 256 thr, 4 waves in a row. Tile M=64(co) x N=128(px),
// BK=64. LDS 24KB: A groups 0..7 (8KB), B groups 8..23 (16KB); group=1KB,
// frag reads = base + lane*16 (conflict-free). A = scaled weights, B = pixels
// => C/D reg-dim (quad*4+r) = co (contiguous in NHWC) -> bf16x4 stores.
// =====================================================================

// ---------------- conv1: o1p[pad(n)][co] = relu(xT[n][:]·w1s[co][:] + b1)
__global__ __launch_bounds__(256, 4) void k_conv1(const bf16* __restrict__ xT,
                                                  const bf16* __restrict__ w1s,
                                                  const float* __restrict__ b1,
                                                  bf16* __restrict__ o1p) {
  __shared__ char smem[24576];
  const int tid = threadIdx.x, wave = tid >> 6, lane = tid & 63;
  const int quad = lane >> 4, l16 = lane & 15;
  const int Nt = blockIdx.x, Mt = blockIdx.y;   // Nt: pixel tile (196), Mt: co tile (4)

  const bf16* gb[6];
#pragma unroll
  for (int i = 0; i < 6; ++i) {
    int g = wave * 6 + i;
    int koff = g < 8 ? ((g & 1) * 4 + quad) * 8 : (((g - 8) & 1) * 4 + quad) * 8;
    if (g < 8) {
      int m = Mt * 64 + (g >> 1) * 16 + l16;
      gb[i] = w1s + (size_t)m * CIN + koff;
    } else {
      int n = Nt * 128 + ((g - 8) >> 1) * 16 + l16;
      gb[i] = xT + (size_t)n * CIN + koff;
    }
  }

  f32x4 acc[4][2];
#pragma unroll
  for (int i = 0; i < 4; ++i)
#pragma unroll
    for (int j = 0; j < 2; ++j) acc[i][j] = {0.f, 0.f, 0.f, 0.f};

  const int lo = lane * 16;
  for (int s = 0; s < CIN / 64; ++s) {
#pragma unroll
    for (int i = 0; i < 6; ++i) gl16(gb[i] + s * 64, smem + (wave * 6 + i) * 1024);
    __syncthreads();
    bf16x8 a[4][2], b[2][2];
#pragma unroll
    for (int mi = 0; mi < 4; ++mi)
#pragma unroll
      for (int h = 0; h < 2; ++h)
        a[mi][h] = *(const bf16x8*)(smem + (mi * 2 + h) * 1024 + lo);
#pragma unroll
    for (int ni = 0; ni < 2; ++ni)
#pragma unroll
      for (int h = 0; h < 2; ++h)
        b[ni][h] = *(const bf16x8*)(smem + 8192 + ((wave * 2 + ni) * 2 + h) * 1024 + lo);
#pragma unroll
    for (int h = 0; h < 2; ++h)
#pragma unroll
      for (int mi = 0; mi < 4; ++mi)
#pragma unroll
        for (int ni = 0; ni < 2; ++ni)
          acc[mi][ni] = __builtin_amdgcn_mfma_f32_16x16x32_bf16(a[mi][h], b[ni][h], acc[mi][ni], 0, 0, 0);
    __syncthreads();
  }

#pragma unroll
  for (int ni = 0; ni < 2; ++ni) {
    int n = Nt * 128 + wave * 32 + ni * 16 + l16;          // pixel
    int nbi = n / HW, p = n - nbi * HW;
    int hh = p / WIMG, ww = p - hh * WIMG;
    bf16* dst = o1p + ((size_t)nbi * PHW + (hh + 1) * PW + (ww + 1)) * CB;
#pragma unroll
    for (int mi = 0; mi < 4; ++mi) {
      int co = Mt * 64 + mi * 16 + quad * 4;
      float4 b4 = *(const float4*)(b1 + co);
      bf16x4 v;
      v[0] = (bf16)fmaxf(acc[mi][ni][0] + b4.x, 0.f);
      v[1] = (bf16)fmaxf(acc[mi][ni][1] + b4.y, 0.f);
      v[2] = (bf16)fmaxf(acc[mi][ni][2] + b4.z, 0.f);
      v[3] = (bf16)fmaxf(acc[mi][ni][3] + b4.w, 0.f);
      *(bf16x4*)(dst + co) = v;
    }
  }
}

// ---------------- conv2: 3x3 SAME over padded o1p. M=64(co) x N=128(px), K=9*256.
__global__ __launch_bounds__(256, 4) void k_conv2(const bf16* __restrict__ o1p,
                                                  const bf16* __restrict__ w2s,
                                                  const float* __restrict__ b2,
                                                  bf16* __restrict__ o2) {
  __shared__ char smem[24576];
  const int tid = threadIdx.x, wave = tid >> 6, lane = tid & 63;
  const int quad = lane >> 4, l16 = lane & 15;
  const int Nt = blockIdx.x, Mt = blockIdx.y;

  const bf16* gb[6];
  bool isA[6];
#pragma unroll
  for (int i = 0; i < 6; ++i) {
    int g = wave * 6 + i;
    isA[i] = g < 8;
    if (g < 8) {
      int m = Mt * 64 + (g >> 1) * 16 + l16;
      gb[i] = w2s + (size_t)m * (9 * CB) + ((g & 1) * 4 + quad) * 8;
    } else {
      int n = Nt * 128 + ((g - 8) >> 1) * 16 + l16;
      int nbi = n / HW, p = n - nbi * HW;
      int hh = p / WIMG, ww = p - hh * WIMG;
      int pp = nbi * PHW + (hh + 1) * PW + (ww + 1);
      gb[i] = o1p + (size_t)pp * CB + (((g - 8) & 1) * 4 + quad) * 8;
    }
  }

  f32x4 acc[4][2];
#pragma unroll
  for (int i = 0; i < 4; ++i)
#pragma unroll
    for (int j = 0; j < 2; ++j) acc[i][j] = {0.f, 0.f, 0.f, 0.f};

  const int lo = lane * 16;
  for (int s = 0; s < 36; ++s) {
    int rs = s >> 2;
    int aoff = ((rs / 3) - 1) * PW + (rs % 3) - 1;
    int soffA = s * 64;
    int soffB = aoff * CB + (s & 3) * 64;
#pragma unroll
    for (int i = 0; i < 6; ++i)
      gl16(gb[i] + (isA[i] ? soffA : soffB), smem + (wave * 6 + i) * 1024);
    __syncthreads();
    bf16x8 a[4][2], b[2][2];
#pragma unroll
    for (int mi = 0; mi < 4; ++mi)
#pragma unroll
      for (int h = 0; h < 2; ++h)
        a[mi][h] = *(const bf16x8*)(smem + (mi * 2 + h) * 1024 + lo);
#pragma unroll
    for (int ni = 0; ni < 2; ++ni)
#pragma unroll
      for (int h = 0; h < 2; ++h)
        b[ni][h] = *(const bf16x8*)(smem + 8192 + ((wave * 2 + ni) * 2 + h) * 1024 + lo);
#pragma unroll
    for (int h = 0; h < 2; ++h)
#pragma unroll
      for (int mi = 0; mi < 4; ++mi)
#pragma unroll
        for (int ni = 0; ni < 2; ++ni)
          acc[mi][ni] = __builtin_amdgcn_mfma_f32_16x16x32_bf16(a[mi][h], b[ni][h], acc[mi][ni], 0, 0, 0);
    __syncthreads();
  }

#pragma unroll
  for (int ni = 0; ni < 2; ++ni) {
    int n = Nt * 128 + wave * 32 + ni * 16 + l16;          // pixel
    bf16* dst = o2 + (size_t)n * CB;
#pragma unroll
    for (int mi = 0; mi < 4; ++mi) {
      int co = Mt * 64 + mi * 16 + quad * 4;
      float4 b4 = *(const float4*)(b2 + co);
      bf16x4 v;
      v[0] = (bf16)fmaxf(acc[mi][ni][0] + b4.x, 0.f);
      v[1] = (bf16)fmaxf(acc[mi][ni][1] + b4.y, 0.f);
      v[2] = (bf16)fmaxf(acc[mi][ni][2] + b4.z, 0.f);
      v[3] = (bf16)fmaxf(acc[mi][ni][3] + b4.w, 0.f);
      *(bf16x4*)(dst + co) = v;
    }
  }
}

// =====================================================================
// conv3: A = o2 (M = 25088 flattened pixels, exact x128 -> no predicates),
// B = w3s (N = 1024 co), K = 256. Reg-dim = pixel -> float4 residual load +
// float4 store into fp32 NCHW out. Block 128x128, 4 waves 2x2, LDS 32KB.
// =====================================================================
__global__ __launch_bounds__(256, 3) void k_conv3(const bf16* __restrict__ o2,
                                                  const bf16* __restrict__ w3s,
                                                  const float* __restrict__ b3,
                                                  const float* __restrict__ x,
                                                  float* __restrict__ out) {
  __shared__ char smem[32768];
  const int tid = threadIdx.x, wave = tid >> 6, lane = tid & 63;
  const int quad = lane >> 4, l16 = lane & 15;
  const int wr = wave >> 1, wc = wave & 1;
  const int Mt = blockIdx.x, Nt = blockIdx.y;   // Mt: pixel tile (196), Nt: co tile (8)

  const bf16* gb[8];
  char* lb = smem + wave * 8192;
#pragma unroll
  for (int i = 0; i < 8; ++i) {
    int g = wave * 8 + i;
    if (g < 16) {
      int m = Mt * 128 + (g >> 1) * 16 + l16;              // pixel row
      gb[i] = o2 + (size_t)m * CB + ((g & 1) * 4 + quad) * 8;
    } else {
      int n = Nt * 128 + ((g - 16) >> 1) * 16 + l16;       // co row
      gb[i] = w3s + (size_t)n * CB + (((g - 16) & 1) * 4 + quad) * 8;
    }
  }

  f32x4 acc[4][4];
#pragma unroll
  for (int i = 0; i < 4; ++i)
#pragma unroll
    for (int j = 0; j < 4; ++j) acc[i][j] = {0.f, 0.f, 0.f, 0.f};

  const int lo = lane * 16;
  for (int s = 0; s < CB / 64; ++s) {
#pragma unroll
    for (int i = 0; i < 8; ++i) gl16(gb[i] + s * 64, lb + i * 1024);
    __syncthreads();
    bf16x8 a[4][2], b[4][2];
#pragma unroll
    for (int mi = 0; mi < 4; ++mi)
#pragma unroll
      for (int h = 0; h < 2; ++h)
        a[mi][h] = *(const bf16x8*)(smem + ((wr * 4 + mi) * 2 + h) * 1024 + lo);
#pragma unroll
    for (int ni = 0; ni < 4; ++ni)
#pragma unroll
      for (int h = 0; h < 2; ++h)
        b[ni][h] = *(const bf16x8*)(smem + 16384 + ((wc * 4 + ni) * 2 + h) * 1024 + lo);
#pragma unroll
    for (int h = 0; h < 2; ++h)
#pragma unroll
      for (int mi = 0; mi < 4; ++mi)
#pragma unroll
        for (int ni = 0; ni < 4; ++ni)
          acc[mi][ni] = __builtin_amdgcn_mfma_f32_16x16x32_bf16(a[mi][h], b[ni][h], acc[mi][ni], 0, 0, 0);
    __syncthreads();
  }

  float bb[4];
  int cob[4];
#pragma unroll
  for (int ni = 0; ni < 4; ++ni) {
    cob[ni] = Nt * 128 + wc * 64 + ni * 16 + l16;
    bb[ni] = b3[cob[ni]];
  }
#pragma unroll
  for (int mi = 0; mi < 4; ++mi) {
    int m = Mt * 128 + wr * 64 + mi * 16 + quad * 4;       // flattened pixel, %4==0
    int nbi = m / HW, p = m - nbi * HW;                    // p..p+3 same image (784%4==0)
#pragma unroll
    for (int ni = 0; ni < 4; ++ni) {
      size_t off = ((size_t)nbi * COUT + cob[ni]) * HW + p;
      float4 xv = *(const float4*)(x + off);
      float4 o;
      o.x = fmaxf(acc[mi][ni][0] + bb[ni] + xv.x, 0.f);
      o.y = fmaxf(acc[mi][ni][1] + bb[ni] + xv.y, 0.f);
      o.z = fmaxf(acc[mi][ni][2] + bb[ni] + xv.z, 0.f);
      o.w = fmaxf(acc[mi][ni][3] + bb[ni] + xv.w, 0.f);
      *(float4*)(out + off) = o;
    }
  }
}

extern "C" void kernel_launch(void* const* d_in, const int* in_sizes, int n_in,
                              void* d_out, int out_size, void* d_ws, size_t ws_size,
                              hipStream_t stream) {
  const float* x  = (const float*)d_in[0];
  const float* w1 = (const float*)d_in[1];
  const float* w2 = (const float*)d_in[2];
  const float* w3 = (const float*)d_in[3];
  const float* s1 = (const float*)d_in[4];
  const float* b1 = (const float*)d_in[5];
  const float* s2 = (const float*)d_in[6];
  const float* b2 = (const float*)d_in[7];
  const float* s3 = (const float*)d_in[8];
  const float* b3 = (const float*)d_in[9];
  float* out = (float*)d_out;

  char* ws = (char*)d_ws;
  // layout: xT/o2 share [0, 51,380,224) (xT dead before conv2 writes o2)
  // o1p at 51,380,224 (14,745,600) | w2s 66,125,824 (1,179,648)
  // w1s 67,305,472 (524,288) | w3s 67,829,760 (524,288)
  bf16* xT  = (bf16*)(ws);
  bf16* o2  = (bf16*)(ws);
  bf16* o1p = (bf16*)(ws + 51380224);
  bf16* w2s = (bf16*)(ws + 66125824);
  bf16* w1s = (bf16*)(ws + 67305472);
  bf16* w3s = (bf16*)(ws + 67829760);

  k_zero<<<dim3(3600, 1, 1), 256, 0, stream>>>((uint4*)o1p, 921600);
  k_transpose<<<dim3(13, 16, NB), 256, 0, stream>>>(x, xT);
  k_w2s<<<dim3(2304, 1, 1), 256, 0, stream>>>(w2, s2, w2s);
  k_wscale<<<dim3(256, 1, 1), 256, 0, stream>>>(w1, s1, w1s, CB * CIN, 10);
  k_wscale<<<dim3(256, 1, 1), 256, 0, stream>>>(w3, s3, w3s, COUT * CB, 8);
  k_conv1<<<dim3(196, 4, 1), 256, 0, stream>>>(xT, w1s, b1, o1p);
  k_conv2<<<dim3(196, 4, 1), 256, 0, stream>>>(o1p, w2s, b2, o2);
  k_conv3<<<dim3(196, 8, 1), 256, 0, stream>>>(o2, w3s, b3, x, out);
}